// Round 1
// 12755.608 us; speedup vs baseline: 1.1615x; 1.1615x over previous
//
#include <hip/hip_runtime.h>

// ---------------------------------------------------------------------------
// MultilayerGRU: B=32, S=4096, H=256, O=256, L=2
// Round 6: 8-wave scan (512 thr, 2 waves/SIMD) + LDS-staged XS prefetch.
//   - per-wave weight residency 384 -> 192 VGPRs (2 nt-tiles/wave)
//   - XS x-side staged via global_load_lds double-buffer (frees 48 VGPRs),
//     drained by vmcnt(0) folded into the end-of-step barrier (spill-safe)
//   - x-side pre-added into MFMA accumulator init (saves adds)
// gemm3 identical except the XS scatter (3 planes x 4096 per (t,wg)).
// ---------------------------------------------------------------------------

typedef __attribute__((ext_vector_type(8))) short short8;
typedef __attribute__((ext_vector_type(4))) float f32x4;

#define TC      256
#define NCHUNK  16
#define SSZ     4096
#define LW      (256*256)

#define SIGSC  (-1.44269504089f)   // -log2(e): sigmoid(x) = rcp(1+exp2(-log2e*x))
#define TANHSC ( 2.88539008178f)   // 2*log2(e): tanh(x) = 1 - 2*rcp(exp2(2log2e*x)+1)

__device__ __forceinline__ float bf2f(unsigned short u) {
    union { unsigned int i; float f; } v; v.i = ((unsigned int)u) << 16; return v.f;
}
__device__ __forceinline__ unsigned short f2bf(float f) {        // RNE
    union { float f; unsigned int i; } v; v.f = f;
    v.i += 0x7fff + ((v.i >> 16) & 1);
    return (unsigned short)(v.i >> 16);
}
__device__ __forceinline__ unsigned int pkbf(float lo, float hi) {
    union { float f; unsigned int i; } a, b; a.f = lo; b.f = hi;
    return __builtin_amdgcn_perm(b.i + 0x8000u, a.i + 0x8000u, 0x07060302);
}
__device__ __forceinline__ short8 cvt8s(const float* p, float s) {
    float4 a = *(const float4*)p;
    float4 b = *(const float4*)(p + 4);
    short8 r;
    r[0] = (short)f2bf(a.x * s); r[1] = (short)f2bf(a.y * s);
    r[2] = (short)f2bf(a.z * s); r[3] = (short)f2bf(a.w * s);
    r[4] = (short)f2bf(b.x * s); r[5] = (short)f2bf(b.y * s);
    r[6] = (short)f2bf(b.z * s); r[7] = (short)f2bf(b.w * s);
    return r;
}
// LDS-only barrier (no vmcnt drain).
__device__ __forceinline__ void wg_barrier() {
    asm volatile("s_waitcnt lgkmcnt(0)" ::: "memory");
    __builtin_amdgcn_s_barrier();
}
// async global->LDS, 16 B per lane; LDS dest = uniform base + lane*16
__device__ __forceinline__ void gl_lds16(const unsigned short* g, unsigned short* l) {
    __builtin_amdgcn_global_load_lds(
        (const __attribute__((address_space(1))) unsigned int*)g,
        (__attribute__((address_space(3))) unsigned int*)l,
        16, 0, 0);
}

// ---------------------------------------------------------------------------
// Fused GEMM dispatch, role by blockIdx.y:
//   jt  0..11 : XS0(c)   = x-side layer 0, chunk c        (c <= 15)
//   jt 12..23 : XS1(c-1) = x-side layer 1 from Hc0        (1 <= c <= 16)
//   jt 24..27 : y(c-2)   = output projection from Hc1     (c >= 2)
// XS layout (per t, wgs): 3 gate-planes x 4096 shorts; thread stid owns
// shorts [stid*8 .. stid*8+7] of each plane (stid = swv*64+sqr*16+scl).
// ---------------------------------------------------------------------------
__global__ __launch_bounds__(256, 2) void gemm3(
    const float* __restrict__ x,
    const unsigned short* __restrict__ Hc0, const unsigned short* __restrict__ Hc1,
    const float* __restrict__ Wxz, const float* __restrict__ Wxr, const float* __restrict__ Wxg,
    const float* __restrict__ bz,  const float* __restrict__ br,  const float* __restrict__ bg,
    const float* __restrict__ Why, const float* __restrict__ by,
    unsigned short* __restrict__ XS0, unsigned short* __restrict__ XS1,
    float* __restrict__ out, int c)
{
    __shared__ unsigned short Alds[64 * 256];
    __shared__ unsigned short Wlds[64 * 256];

    const int jt = blockIdx.y;
    const void* Aptr; int a_mode, c0abs = 0, o_mode, jtl;
    const float *w0, *w1, *w2, *b0, *b1, *b2; void* Optr;
    if (jt < 12) {
        if (c > 15) return;
        Aptr = x; a_mode = 0; c0abs = c * TC;
        w0 = Wxz; w1 = Wxr; w2 = Wxg; b0 = bz; b1 = br; b2 = bg;
        Optr = XS0; o_mode = 0; jtl = jt;
    } else if (jt < 24) {
        if (c < 1 || c > 16) return;
        Aptr = Hc0; a_mode = 1;
        w0 = Wxz + LW; w1 = Wxr + LW; w2 = Wxg + LW;
        b0 = bz + 256; b1 = br + 256; b2 = bg + 256;
        Optr = XS1; o_mode = 0; jtl = jt - 12;
    } else {
        if (c < 2) return;
        Aptr = Hc1; a_mode = 1; c0abs = (c - 2) * TC;
        w0 = Why; w1 = Why; w2 = Why; b0 = by; b1 = by; b2 = by;
        Optr = out; o_mode = 1; jtl = jt - 24;
    }

    const int tid = threadIdx.x;
    const int mt = blockIdx.x;

    for (int idx = tid; idx < 4096; idx += 256) {
        int row = idx >> 6;
        int kq  = (idx & 63) << 2;
        int sw  = row * 256 + (((((kq >> 3) ^ (row & 7)) << 3)) | (kq & 7));
        if (a_mode == 0) {
            int i = mt * 64 + row; int tc = i >> 5, b = i & 31;
            const float* p = (const float*)Aptr + ((size_t)b * SSZ + (size_t)(c0abs + tc)) * 256 + kq;
            float4 v = *(const float4*)p;
            ushort4 u; u.x = f2bf(v.x); u.y = f2bf(v.y); u.z = f2bf(v.z); u.w = f2bf(v.w);
            *(ushort4*)&Alds[sw] = u;
        } else {
            const unsigned short* p = (const unsigned short*)Aptr + (size_t)(mt * 64 + row) * 256 + kq;
            *(ushort4*)&Alds[sw] = *(const ushort4*)p;
        }
    }
    for (int idx = tid; idx < 4096; idx += 256) {
        int row = idx >> 6;
        int kq  = (idx & 63) << 2;
        int j   = jtl * 64 + row;
        const float* wp = (j < 256) ? w0 : ((j < 512) ? w1 : w2);
        const float* p  = wp + (size_t)(j & 255) * 256 + kq;
        float4 v = *(const float4*)p;
        ushort4 u; u.x = f2bf(v.x); u.y = f2bf(v.y); u.z = f2bf(v.z); u.w = f2bf(v.w);
        int sw = row * 256 + (((((kq >> 3) ^ (row & 7)) << 3)) | (kq & 7));
        *(ushort4*)&Wlds[sw] = u;
    }
    __syncthreads();

    const int lane = tid & 63, wv = tid >> 6;
    const int cl = lane & 15, qr = lane >> 4;
    f32x4 acc[4];
    #pragma unroll
    for (int nt = 0; nt < 4; ++nt) acc[nt] = (f32x4){0.f, 0.f, 0.f, 0.f};

    #pragma unroll
    for (int kt = 0; kt < 8; ++kt) {
        int kb = kt * 4 + qr;
        short8 af = *(const short8*)&Alds[(wv * 16 + cl) * 256 + ((kb ^ (cl & 7)) << 3)];
        #pragma unroll
        for (int nt = 0; nt < 4; ++nt) {
            short8 bf = *(const short8*)&Wlds[(nt * 16 + cl) * 256 + ((kb ^ (cl & 7)) << 3)];
            acc[nt] = __builtin_amdgcn_mfma_f32_16x16x32_bf16(af, bf, acc[nt], 0, 0, 0);
        }
    }

    #pragma unroll
    for (int nt = 0; nt < 4; ++nt) {
        int j = jtl * 64 + nt * 16 + cl;
        const float* bp = (j < 256) ? b0 : ((j < 512) ? b1 : b2);
        float bias = bp[j & 255];
        #pragma unroll
        for (int r = 0; r < 4; ++r) {
            float v = acc[nt][r] + bias;
            int m = mt * 64 + wv * 16 + qr * 4 + r;      // C/D: row=(lane>>4)*4+reg, col=lane&15
            if (o_mode == 0) {
                int t = m >> 5, b = m & 31;
                int wgs = b >> 4, scl = b & 15;          // scan: sample -> lane cl
                int gate = j >> 8, cc = j & 255;
                // scan thread (8 waves): n = swv*32 + snt*16 + sqr*4 + sr
                int swv = cc >> 5, snt = (cc >> 4) & 1, sqr = (cc >> 2) & 3, sr = cc & 3;
                int stid = swv * 64 + sqr * 16 + scl;
                size_t off = (((size_t)((t * 2 + wgs) * 3 + gate)) << 12)
                           + (size_t)stid * 8 + (snt * 4 + sr);
                float gs = (gate < 2) ? SIGSC : TANHSC;
                ((unsigned short*)Optr)[off] = f2bf(v * gs);
            } else {
                int tc = m >> 5, b = m & 31;
                ((float*)Optr)[(size_t)b * (SSZ * 256) + (size_t)(c0abs + tc) * 256 + j] = v;
            }
        }
    }
}

// ---------------------------------------------------------------------------
// Dual-layer GRU scan: blockIdx 0,1 -> layer 0 chunk c; 2,3 -> layer 1 chunk
// c-1. 512 threads = 8 waves (2/SIMD), each wave owns 2 nt-tiles (32 n).
// XS x-side is prefetched one step ahead into LDS via global_load_lds;
// each wave reads only the slab it loaded, drained at the per-step vmcnt(0)
// barrier (count-independent -> safe under spill traffic).
// ---------------------------------------------------------------------------
__global__ __launch_bounds__(512, 2) void scan_dual(
    const unsigned short* __restrict__ XS0, const unsigned short* __restrict__ XS1,
    unsigned short* __restrict__ Hc0, unsigned short* __restrict__ Hc1,
    float* __restrict__ hstate,                // ws [2][32][256] fp32
    const float* __restrict__ hidden_in,       // d_in[1] [32][2][256] fp32
    const float* __restrict__ Whz0, const float* __restrict__ Whr0,
    const float* __restrict__ Whg0,
    int c, float* __restrict__ dout_tail)      // d_out + B*S*O, [32][2][256]
{
    __shared__ unsigned short hA[4096];        // h   [b:16][n:256] bf16, swizzled
    __shared__ unsigned short A2[4096];        // h*r [b:16][n:256]
    __shared__ unsigned short XL[2][3][4096];  // x-side double buffer, 48 KiB

    const int layer = blockIdx.x >> 1;
    const int wg    = blockIdx.x & 1;
    const int chunk = (layer == 0) ? c : c - 1;
    if (chunk < 0 || chunk > 15) return;

    const unsigned short* XS = (layer == 0) ? XS0 : XS1;
    unsigned short* Hout     = (layer == 0) ? Hc0 : Hc1;
    const float* Whz = Whz0 + (size_t)layer * LW;
    const float* Whr = Whr0 + (size_t)layer * LW;
    const float* Whg = Whg0 + (size_t)layer * LW;
    const int first_chunk = (chunk == 0), last_chunk = (chunk == NCHUNK - 1);

    const int tid  = threadIdx.x;
    const int lane = tid & 63, wv = tid >> 6;  // 8 waves
    const int cl   = lane & 15, qr = lane >> 4;
    const int swl  = cl & 7;
    const int b    = wg * 16 + cl;             // this lane's sample

    // weights as A-frags (pre-scaled): A[n][k], n = wv*32 + nt*16 + cl
    short8 wzf[2][8], wrf[2][8], wgf[2][8];
    #pragma unroll
    for (int nt = 0; nt < 2; ++nt) {
        int n = wv * 32 + nt * 16 + cl;
        #pragma unroll
        for (int kt = 0; kt < 8; ++kt) {
            int k0 = kt * 32 + qr * 8;
            wzf[nt][kt] = cvt8s(Whz + (size_t)n * 256 + k0, SIGSC);
            wrf[nt][kt] = cvt8s(Whr + (size_t)n * 256 + k0, SIGSC);
            wgf[nt][kt] = cvt8s(Whg + (size_t)n * 256 + k0, TANHSC);
        }
    }

    // per-nt invariant packed-write offsets: 4 consecutive n
    int wro[2];
    #pragma unroll
    for (int nt = 0; nt < 2; ++nt) {
        int nb = wv * 32 + nt * 16 + qr * 4;
        wro[nt] = cl * 256 + ((((nb >> 3) ^ swl) << 3) | (nb & 4));
    }

    // h master: lane holds h[b][nb..nb+3] per tile (fp32), init hA image
    float hreg[2][4];
    #pragma unroll
    for (int nt = 0; nt < 2; ++nt) {
        int nb = wv * 32 + nt * 16 + qr * 4;
        float4 h4;
        if (first_chunk) h4 = *(const float4*)(hidden_in + (size_t)b * 512 + layer * 256 + nb);
        else             h4 = *(const float4*)(hstate + layer * 8192 + b * 256 + nb);
        hreg[nt][0] = h4.x; hreg[nt][1] = h4.y; hreg[nt][2] = h4.z; hreg[nt][3] = h4.w;
        uint2 p; p.x = pkbf(h4.x, h4.y); p.y = pkbf(h4.z, h4.w);
        *(uint2*)&hA[wro[nt]] = p;
    }

    // per-lane global XS pointer; advances 24576 shorts (= 2 wgs * 3 * 4096)
    const unsigned short* xsg = XS + (size_t)wg * 3 * 4096 + (size_t)tid * 8;
    // prologue: prefetch step 0 into XL[0] (own wave slab only)
    gl_lds16(xsg,        &XL[0][0][wv * 512]);
    gl_lds16(xsg + 4096, &XL[0][1][wv * 512]);
    gl_lds16(xsg + 8192, &XL[0][2][wv * 512]);
    asm volatile("s_waitcnt vmcnt(0) lgkmcnt(0)" ::: "memory");
    __builtin_amdgcn_s_barrier();

    #pragma unroll 1
    for (int t = 0; t < TC; ++t) {
        const int cur = t & 1, nxt = cur ^ 1;
        const unsigned short* xb = &XL[cur][0][tid * 8];
        short8 xz = *(const short8*)xb;            // z-plane (pre-scaled, +bias)
        short8 xr = *(const short8*)(xb + 4096);   // r-plane

        // prefetch t+1 into the other buffer (own wave slab; drained at bar-B)
        const unsigned short* gnx = xsg + ((t + 1 < TC) ? 24576 : 0);
        gl_lds16(gnx,        &XL[nxt][0][wv * 512]);
        gl_lds16(gnx + 4096, &XL[nxt][1][wv * 512]);
        gl_lds16(gnx + 8192, &XL[nxt][2][wv * 512]);
        xsg = gnx;

        // pass 1: z, r  (acc starts at x-side value)
        f32x4 az[2], ar[2];
        #pragma unroll
        for (int nt = 0; nt < 2; ++nt) {
            #pragma unroll
            for (int r = 0; r < 4; ++r) {
                az[nt][r] = bf2f((unsigned short)xz[nt * 4 + r]);
                ar[nt][r] = bf2f((unsigned short)xr[nt * 4 + r]);
            }
        }
        #pragma unroll
        for (int kt = 0; kt < 8; ++kt) {
            int kb = kt * 4 + qr;
            short8 bf = *(const short8*)&hA[cl * 256 + ((kb ^ swl) << 3)];
            az[0] = __builtin_amdgcn_mfma_f32_16x16x32_bf16(wzf[0][kt], bf, az[0], 0, 0, 0);
            ar[0] = __builtin_amdgcn_mfma_f32_16x16x32_bf16(wrf[0][kt], bf, ar[0], 0, 0, 0);
            az[1] = __builtin_amdgcn_mfma_f32_16x16x32_bf16(wzf[1][kt], bf, az[1], 0, 0, 0);
            ar[1] = __builtin_amdgcn_mfma_f32_16x16x32_bf16(wrf[1][kt], bf, ar[1], 0, 0, 0);
        }

        float zs[2][4];
        #pragma unroll
        for (int nt = 0; nt < 2; ++nt) {
            float a2v[4];
            #pragma unroll
            for (int r = 0; r < 4; ++r) {
                zs[nt][r] = __builtin_amdgcn_rcpf(1.0f + __builtin_amdgcn_exp2f(az[nt][r]));
                float rr  = __builtin_amdgcn_rcpf(1.0f + __builtin_amdgcn_exp2f(ar[nt][r]));
                a2v[r] = rr * hreg[nt][r];
            }
            uint2 p; p.x = pkbf(a2v[0], a2v[1]); p.y = pkbf(a2v[2], a2v[3]);
            *(uint2*)&A2[wro[nt]] = p;
        }
        wg_barrier();

        // pass 2: g = (h*r) @ Whg^T  (B = A2 image; acc starts at x-side)
        short8 xg = *(const short8*)(xb + 8192);   // g-plane (XL[cur] still valid)
        f32x4 ag[2];
        #pragma unroll
        for (int nt = 0; nt < 2; ++nt) {
            #pragma unroll
            for (int r = 0; r < 4; ++r)
                ag[nt][r] = bf2f((unsigned short)xg[nt * 4 + r]);
        }
        #pragma unroll
        for (int kt = 0; kt < 8; ++kt) {
            int kb = kt * 4 + qr;
            short8 bf = *(const short8*)&A2[cl * 256 + ((kb ^ swl) << 3)];
            ag[0] = __builtin_amdgcn_mfma_f32_16x16x32_bf16(wgf[0][kt], bf, ag[0], 0, 0, 0);
            ag[1] = __builtin_amdgcn_mfma_f32_16x16x32_bf16(wgf[1][kt], bf, ag[1], 0, 0, 0);
        }
        #pragma unroll
        for (int nt = 0; nt < 2; ++nt) {
            float hn4[4];
            #pragma unroll
            for (int r = 0; r < 4; ++r) {
                float g = 1.0f - 2.0f * __builtin_amdgcn_rcpf(
                              1.0f + __builtin_amdgcn_exp2f(ag[nt][r]));
                float hn = g + zs[nt][r] * (hreg[nt][r] - g);
                hreg[nt][r] = hn;
                hn4[r] = hn;
            }
            uint2 p; p.x = pkbf(hn4[0], hn4[1]); p.y = pkbf(hn4[2], hn4[3]);
            *(uint2*)&hA[wro[nt]] = p;
        }
        // barrier B: hA visible + XS prefetch drained (vmcnt(0) is
        // count-independent -> immune to compiler scratch/spill vmem ops)
        asm volatile("s_waitcnt vmcnt(0) lgkmcnt(0)" ::: "memory");
        __builtin_amdgcn_s_barrier();

        // coalesced Hout[t] from hA image; store left in flight
        {
            int m = tid >> 5, kb2 = tid & 31, xx = m & 7;
            short8 r0 = *(const short8*)&hA[m * 256 + ((kb2 ^ xx) << 3)];
            *(short8*)(Hout + (size_t)(t * 32 + wg * 16 + m) * 256 + kb2 * 8) = r0;
        }
    }

    // persist state; emit final hidden on last chunk
    #pragma unroll
    for (int nt = 0; nt < 2; ++nt) {
        int nb = wv * 32 + nt * 16 + qr * 4;
        float4 h4; h4.x = hreg[nt][0]; h4.y = hreg[nt][1]; h4.z = hreg[nt][2]; h4.w = hreg[nt][3];
        *(float4*)(hstate + layer * 8192 + b * 256 + nb) = h4;
        if (last_chunk)
            *(float4*)(dout_tail + (size_t)b * 512 + layer * 256 + nb) = h4;
    }
}

extern "C" void kernel_launch(void* const* d_in, const int* in_sizes, int n_in,
                              void* d_out, int out_size, void* d_ws, size_t ws_size,
                              hipStream_t stream) {
    const float* x   = (const float*)d_in[0];
    const float* h0  = (const float*)d_in[1];
    const float* Wxz = (const float*)d_in[2];
    const float* Whz = (const float*)d_in[3];
    const float* bz  = (const float*)d_in[4];
    const float* Wxr = (const float*)d_in[5];
    const float* Whr = (const float*)d_in[6];
    const float* br  = (const float*)d_in[7];
    const float* Wxg = (const float*)d_in[8];
    const float* Whg = (const float*)d_in[9];
    const float* bg  = (const float*)d_in[10];
    const float* Why = (const float*)d_in[11];
    const float* by  = (const float*)d_in[12];
    float* out = (float*)d_out;

    char* ws = (char*)d_ws;
    unsigned short* bufA = (unsigned short*)(ws);                    // XS0 12,582,912 B
    unsigned short* bufB = (unsigned short*)(ws + 12582912);         // XS1 12,582,912 B
    unsigned short* Hc0  = (unsigned short*)(ws + 25165824);         //  4,194,304 B
    unsigned short* Hc1  = (unsigned short*)(ws + 29360128);         //  4,194,304 B
    float*          hst  = (float*)(ws + 33554432);                  //     65,536 B
    float* dout_tail = out + (size_t)32 * 4096 * 256;

    // chunk-pipelined: iter i computes XS0(i), XS1(i-1), y(i-2) in one gemm
    // dispatch, then scans layer0(i) + layer1(i-1) concurrently.
    for (int i = 0; i <= 17; ++i) {
        gemm3<<<dim3(128, 28), 256, 0, stream>>>(x, Hc0, Hc1,
                                                 Wxz, Wxr, Wxg, bz, br, bg,
                                                 Why, by, bufA, bufB, out, i);
        if (i <= 16)
            scan_dual<<<4, 512, 0, stream>>>(bufA, bufB, Hc0, Hc1, hst, h0,
                                             Whz, Whr, Whg, i, dout_tail);
    }
}

// Round 2
// 9550.088 us; speedup vs baseline: 1.5514x; 1.3357x over previous
//
#include <hip/hip_runtime.h>

// ---------------------------------------------------------------------------
// MultilayerGRU: B=32, S=4096, H=256, O=256, L=2
// Round 7: register-diet scan. Theory: round-6 was ~5 regs over the 256/wave
// cap (2 waves/SIMD) -> per-step scratch round-trips (5MB/dispatch mystery
// FETCH). Changes (scan only, gemm3 identical to round 6):
//   - g-gate weights moved to LDS (128KB, swizzled, prescaled): regs 192->128
//   - x-side XS: direct global->reg double-buffer (XL + global_load_lds gone)
//     => all barriers are lgkm-only, no vmcnt(0) drain per step
//   - Hout stored directly from packed registers after barrier B (no hA
//     re-read, store off critical path)
// Per-wave regs ~218 (was ~261). LDS 144KB/WG.
// ---------------------------------------------------------------------------

typedef __attribute__((ext_vector_type(8))) short short8;
typedef __attribute__((ext_vector_type(4))) float f32x4;

#define TC      256
#define NCHUNK  16
#define SSZ     4096
#define LW      (256*256)

#define SIGSC  (-1.44269504089f)   // -log2(e): sigmoid(x) = rcp(1+exp2(-log2e*x))
#define TANHSC ( 2.88539008178f)   // 2*log2(e): tanh(x) = 1 - 2*rcp(exp2(2log2e*x)+1)

__device__ __forceinline__ float bf2f(unsigned short u) {
    union { unsigned int i; float f; } v; v.i = ((unsigned int)u) << 16; return v.f;
}
__device__ __forceinline__ unsigned short f2bf(float f) {        // RNE
    union { float f; unsigned int i; } v; v.f = f;
    v.i += 0x7fff + ((v.i >> 16) & 1);
    return (unsigned short)(v.i >> 16);
}
__device__ __forceinline__ unsigned int pkbf(float lo, float hi) {
    union { float f; unsigned int i; } a, b; a.f = lo; b.f = hi;
    return __builtin_amdgcn_perm(b.i + 0x8000u, a.i + 0x8000u, 0x07060302);
}
__device__ __forceinline__ short8 cvt8s(const float* p, float s) {
    float4 a = *(const float4*)p;
    float4 b = *(const float4*)(p + 4);
    short8 r;
    r[0] = (short)f2bf(a.x * s); r[1] = (short)f2bf(a.y * s);
    r[2] = (short)f2bf(a.z * s); r[3] = (short)f2bf(a.w * s);
    r[4] = (short)f2bf(b.x * s); r[5] = (short)f2bf(b.y * s);
    r[6] = (short)f2bf(b.z * s); r[7] = (short)f2bf(b.w * s);
    return r;
}
// LDS-only barrier: no vmcnt drain anywhere in the scan loop now.
__device__ __forceinline__ void wg_barrier() {
    asm volatile("s_waitcnt lgkmcnt(0)" ::: "memory");
    __builtin_amdgcn_s_barrier();
}

// ---------------------------------------------------------------------------
// Fused GEMM dispatch, role by blockIdx.y (IDENTICAL to round 6):
//   jt  0..11 : XS0(c)   = x-side layer 0, chunk c        (c <= 15)
//   jt 12..23 : XS1(c-1) = x-side layer 1 from Hc0        (1 <= c <= 16)
//   jt 24..27 : y(c-2)   = output projection from Hc1     (c >= 2)
// XS layout (per t, wgs): 3 gate-planes x 4096 shorts; scan thread stid owns
// shorts [stid*8 .. stid*8+7] of each plane.
// ---------------------------------------------------------------------------
__global__ __launch_bounds__(256, 2) void gemm3(
    const float* __restrict__ x,
    const unsigned short* __restrict__ Hc0, const unsigned short* __restrict__ Hc1,
    const float* __restrict__ Wxz, const float* __restrict__ Wxr, const float* __restrict__ Wxg,
    const float* __restrict__ bz,  const float* __restrict__ br,  const float* __restrict__ bg,
    const float* __restrict__ Why, const float* __restrict__ by,
    unsigned short* __restrict__ XS0, unsigned short* __restrict__ XS1,
    float* __restrict__ out, int c)
{
    __shared__ unsigned short Alds[64 * 256];
    __shared__ unsigned short Wlds[64 * 256];

    const int jt = blockIdx.y;
    const void* Aptr; int a_mode, c0abs = 0, o_mode, jtl;
    const float *w0, *w1, *w2, *b0, *b1, *b2; void* Optr;
    if (jt < 12) {
        if (c > 15) return;
        Aptr = x; a_mode = 0; c0abs = c * TC;
        w0 = Wxz; w1 = Wxr; w2 = Wxg; b0 = bz; b1 = br; b2 = bg;
        Optr = XS0; o_mode = 0; jtl = jt;
    } else if (jt < 24) {
        if (c < 1 || c > 16) return;
        Aptr = Hc0; a_mode = 1;
        w0 = Wxz + LW; w1 = Wxr + LW; w2 = Wxg + LW;
        b0 = bz + 256; b1 = br + 256; b2 = bg + 256;
        Optr = XS1; o_mode = 0; jtl = jt - 12;
    } else {
        if (c < 2) return;
        Aptr = Hc1; a_mode = 1; c0abs = (c - 2) * TC;
        w0 = Why; w1 = Why; w2 = Why; b0 = by; b1 = by; b2 = by;
        Optr = out; o_mode = 1; jtl = jt - 24;
    }

    const int tid = threadIdx.x;
    const int mt = blockIdx.x;

    for (int idx = tid; idx < 4096; idx += 256) {
        int row = idx >> 6;
        int kq  = (idx & 63) << 2;
        int sw  = row * 256 + (((((kq >> 3) ^ (row & 7)) << 3)) | (kq & 7));
        if (a_mode == 0) {
            int i = mt * 64 + row; int tc = i >> 5, b = i & 31;
            const float* p = (const float*)Aptr + ((size_t)b * SSZ + (size_t)(c0abs + tc)) * 256 + kq;
            float4 v = *(const float4*)p;
            ushort4 u; u.x = f2bf(v.x); u.y = f2bf(v.y); u.z = f2bf(v.z); u.w = f2bf(v.w);
            *(ushort4*)&Alds[sw] = u;
        } else {
            const unsigned short* p = (const unsigned short*)Aptr + (size_t)(mt * 64 + row) * 256 + kq;
            *(ushort4*)&Alds[sw] = *(const ushort4*)p;
        }
    }
    for (int idx = tid; idx < 4096; idx += 256) {
        int row = idx >> 6;
        int kq  = (idx & 63) << 2;
        int j   = jtl * 64 + row;
        const float* wp = (j < 256) ? w0 : ((j < 512) ? w1 : w2);
        const float* p  = wp + (size_t)(j & 255) * 256 + kq;
        float4 v = *(const float4*)p;
        ushort4 u; u.x = f2bf(v.x); u.y = f2bf(v.y); u.z = f2bf(v.z); u.w = f2bf(v.w);
        int sw = row * 256 + (((((kq >> 3) ^ (row & 7)) << 3)) | (kq & 7));
        *(ushort4*)&Wlds[sw] = u;
    }
    __syncthreads();

    const int lane = tid & 63, wv = tid >> 6;
    const int cl = lane & 15, qr = lane >> 4;
    f32x4 acc[4];
    #pragma unroll
    for (int nt = 0; nt < 4; ++nt) acc[nt] = (f32x4){0.f, 0.f, 0.f, 0.f};

    #pragma unroll
    for (int kt = 0; kt < 8; ++kt) {
        int kb = kt * 4 + qr;
        short8 af = *(const short8*)&Alds[(wv * 16 + cl) * 256 + ((kb ^ (cl & 7)) << 3)];
        #pragma unroll
        for (int nt = 0; nt < 4; ++nt) {
            short8 bf = *(const short8*)&Wlds[(nt * 16 + cl) * 256 + ((kb ^ (cl & 7)) << 3)];
            acc[nt] = __builtin_amdgcn_mfma_f32_16x16x32_bf16(af, bf, acc[nt], 0, 0, 0);
        }
    }

    #pragma unroll
    for (int nt = 0; nt < 4; ++nt) {
        int j = jtl * 64 + nt * 16 + cl;
        const float* bp = (j < 256) ? b0 : ((j < 512) ? b1 : b2);
        float bias = bp[j & 255];
        #pragma unroll
        for (int r = 0; r < 4; ++r) {
            float v = acc[nt][r] + bias;
            int m = mt * 64 + wv * 16 + qr * 4 + r;      // C/D: row=(lane>>4)*4+reg, col=lane&15
            if (o_mode == 0) {
                int t = m >> 5, b = m & 31;
                int wgs = b >> 4, scl = b & 15;          // scan: sample -> lane cl
                int gate = j >> 8, cc = j & 255;
                // scan thread (8 waves): n = swv*32 + snt*16 + sqr*4 + sr
                int swv = cc >> 5, snt = (cc >> 4) & 1, sqr = (cc >> 2) & 3, sr = cc & 3;
                int stid = swv * 64 + sqr * 16 + scl;
                size_t off = (((size_t)((t * 2 + wgs) * 3 + gate)) << 12)
                           + (size_t)stid * 8 + (snt * 4 + sr);
                float gs = (gate < 2) ? SIGSC : TANHSC;
                ((unsigned short*)Optr)[off] = f2bf(v * gs);
            } else {
                int tc = m >> 5, b = m & 31;
                ((float*)Optr)[(size_t)b * (SSZ * 256) + (size_t)(c0abs + tc) * 256 + j] = v;
            }
        }
    }
}

// ---------------------------------------------------------------------------
// Dual-layer GRU scan: blockIdx 0,1 -> layer 0 chunk c; 2,3 -> layer 1 chunk
// c-1. 512 threads = 8 waves (2/SIMD), each wave owns 2 nt-tiles (32 n).
// z/r weights in registers (128 VGPR); g weights in LDS (128KB swizzled).
// x-side: direct global->reg, one step ahead. Barriers are lgkm-only.
// ---------------------------------------------------------------------------
__global__ __launch_bounds__(512, 2) void scan_dual(
    const unsigned short* __restrict__ XS0, const unsigned short* __restrict__ XS1,
    unsigned short* __restrict__ Hc0, unsigned short* __restrict__ Hc1,
    float* __restrict__ hstate,                // ws [2][32][256] fp32
    const float* __restrict__ hidden_in,       // d_in[1] [32][2][256] fp32
    const float* __restrict__ Whz0, const float* __restrict__ Whr0,
    const float* __restrict__ Whg0,
    int c, float* __restrict__ dout_tail)      // d_out + B*S*O, [32][2][256]
{
    __shared__ unsigned short hA[4096];        // h   [b:16][n:256] bf16, swizzled
    __shared__ unsigned short A2[4096];        // h*r [b:16][n:256]
    __shared__ unsigned short Wg[65536];       // Whg bf16 prescaled, swizzled, 128KB

    const int layer = blockIdx.x >> 1;
    const int wg    = blockIdx.x & 1;
    const int chunk = (layer == 0) ? c : c - 1;
    if (chunk < 0 || chunk > 15) return;

    const unsigned short* XS = (layer == 0) ? XS0 : XS1;
    unsigned short* Hout     = (layer == 0) ? Hc0 : Hc1;
    const float* Whz = Whz0 + (size_t)layer * LW;
    const float* Whr = Whr0 + (size_t)layer * LW;
    const float* Whg = Whg0 + (size_t)layer * LW;
    const int first_chunk = (chunk == 0), last_chunk = (chunk == NCHUNK - 1);

    const int tid  = threadIdx.x;
    const int lane = tid & 63, wv = tid >> 6;  // 8 waves
    const int cl   = lane & 15, qr = lane >> 4;
    const int swl  = cl & 7;
    const int b    = wg * 16 + cl;             // this lane's sample

    // ---- stage g-gate weights into LDS (prescaled by TANHSC, swizzled) ----
    for (int idx = tid; idx < 16384; idx += 512) {
        int n  = idx >> 6;
        int kq = (idx & 63) << 2;
        float4 v = *(const float4*)(Whg + (size_t)n * 256 + kq);
        ushort4 u;
        u.x = f2bf(v.x * TANHSC); u.y = f2bf(v.y * TANHSC);
        u.z = f2bf(v.z * TANHSC); u.w = f2bf(v.w * TANHSC);
        int sw = n * 256 + (((((kq >> 3) ^ (n & 7)) << 3)) | (kq & 7));
        *(ushort4*)&Wg[sw] = u;
    }

    // ---- z/r weights as register A-frags (pre-scaled by SIGSC) ----
    short8 wzf[2][8], wrf[2][8];
    #pragma unroll
    for (int nt = 0; nt < 2; ++nt) {
        int n = wv * 32 + nt * 16 + cl;
        #pragma unroll
        for (int kt = 0; kt < 8; ++kt) {
            int k0 = kt * 32 + qr * 8;
            wzf[nt][kt] = cvt8s(Whz + (size_t)n * 256 + k0, SIGSC);
            wrf[nt][kt] = cvt8s(Whr + (size_t)n * 256 + k0, SIGSC);
        }
    }

    // per-nt invariant packed-write offsets: 4 consecutive n
    int wro[2];
    #pragma unroll
    for (int nt = 0; nt < 2; ++nt) {
        int nb = wv * 32 + nt * 16 + qr * 4;
        wro[nt] = cl * 256 + ((((nb >> 3) ^ swl) << 3) | (nb & 4));
    }

    // h master: lane holds h[b][nb..nb+3] per tile (fp32), init hA image
    float hreg[2][4];
    #pragma unroll
    for (int nt = 0; nt < 2; ++nt) {
        int nb = wv * 32 + nt * 16 + qr * 4;
        float4 h4;
        if (first_chunk) h4 = *(const float4*)(hidden_in + (size_t)b * 512 + layer * 256 + nb);
        else             h4 = *(const float4*)(hstate + layer * 8192 + b * 256 + nb);
        hreg[nt][0] = h4.x; hreg[nt][1] = h4.y; hreg[nt][2] = h4.z; hreg[nt][3] = h4.w;
        uint2 p; p.x = pkbf(h4.x, h4.y); p.y = pkbf(h4.z, h4.w);
        *(uint2*)&hA[wro[nt]] = p;
    }

    // x-side: per-lane pointer, 3 planes of 4096 shorts per (t,wg) block,
    // consecutive t are 24576 shorts apart. Load t=0 now.
    const unsigned short* xp = XS + (size_t)wg * 12288 + (size_t)tid * 8;
    short8 xz = *(const short8*)(xp);
    short8 xr = *(const short8*)(xp + 4096);
    short8 xg = *(const short8*)(xp + 8192);

    wg_barrier();   // hA init + Wg fill visible

    uint2 hpk[2];   // packed h(t) held across barrier B for the Hout store
    const size_t holane = (size_t)(wg * 16 + cl) * 256 + (size_t)wv * 32 + (size_t)qr * 4;

    #pragma unroll 1
    for (int t = 0; t < TC; ++t) {
        // Hout(t-1): direct store from registers, off the critical path
        if (t) {
            unsigned short* hp = Hout + (size_t)(t - 1) * 8192 + holane;
            *(uint2*)hp        = hpk[0];
            *(uint2*)(hp + 16) = hpk[1];
        }

        // prefetch x(t+1) into regs (consumed next iteration)
        const unsigned short* xq = xp + (size_t)((t + 1 < TC) ? t + 1 : t) * 24576;
        short8 nz = *(const short8*)(xq);
        short8 nr = *(const short8*)(xq + 4096);
        short8 ng = *(const short8*)(xq + 8192);

        // pass 1: z, r  (acc starts at x-side value)
        f32x4 az[2], ar[2];
        #pragma unroll
        for (int nt = 0; nt < 2; ++nt) {
            #pragma unroll
            for (int r = 0; r < 4; ++r) {
                az[nt][r] = bf2f((unsigned short)xz[nt * 4 + r]);
                ar[nt][r] = bf2f((unsigned short)xr[nt * 4 + r]);
            }
        }
        #pragma unroll
        for (int kt = 0; kt < 8; ++kt) {
            int kb = kt * 4 + qr;
            short8 bf = *(const short8*)&hA[cl * 256 + ((kb ^ swl) << 3)];
            az[0] = __builtin_amdgcn_mfma_f32_16x16x32_bf16(wzf[0][kt], bf, az[0], 0, 0, 0);
            ar[0] = __builtin_amdgcn_mfma_f32_16x16x32_bf16(wrf[0][kt], bf, ar[0], 0, 0, 0);
            az[1] = __builtin_amdgcn_mfma_f32_16x16x32_bf16(wzf[1][kt], bf, az[1], 0, 0, 0);
            ar[1] = __builtin_amdgcn_mfma_f32_16x16x32_bf16(wrf[1][kt], bf, ar[1], 0, 0, 0);
        }

        float zs[2][4];
        #pragma unroll
        for (int nt = 0; nt < 2; ++nt) {
            float a2v[4];
            #pragma unroll
            for (int r = 0; r < 4; ++r) {
                zs[nt][r] = __builtin_amdgcn_rcpf(1.0f + __builtin_amdgcn_exp2f(az[nt][r]));
                float rr  = __builtin_amdgcn_rcpf(1.0f + __builtin_amdgcn_exp2f(ar[nt][r]));
                a2v[r] = rr * hreg[nt][r];
            }
            uint2 p; p.x = pkbf(a2v[0], a2v[1]); p.y = pkbf(a2v[2], a2v[3]);
            *(uint2*)&A2[wro[nt]] = p;
        }
        wg_barrier();

        // pass 2: g = (h*r) @ Whg^T   (A-frags from LDS Wg, B from A2)
        f32x4 ag[2];
        #pragma unroll
        for (int nt = 0; nt < 2; ++nt) {
            #pragma unroll
            for (int r = 0; r < 4; ++r)
                ag[nt][r] = bf2f((unsigned short)xg[nt * 4 + r]);
        }
        #pragma unroll
        for (int kt = 0; kt < 8; ++kt) {
            int kb = kt * 4 + qr;
            int ko = (kb ^ swl) << 3;
            short8 bf  = *(const short8*)&A2[cl * 256 + ko];
            short8 af0 = *(const short8*)&Wg[(wv * 32 + cl) * 256 + ko];
            short8 af1 = *(const short8*)&Wg[(wv * 32 + 16 + cl) * 256 + ko];
            ag[0] = __builtin_amdgcn_mfma_f32_16x16x32_bf16(af0, bf, ag[0], 0, 0, 0);
            ag[1] = __builtin_amdgcn_mfma_f32_16x16x32_bf16(af1, bf, ag[1], 0, 0, 0);
        }
        #pragma unroll
        for (int nt = 0; nt < 2; ++nt) {
            float hn4[4];
            #pragma unroll
            for (int r = 0; r < 4; ++r) {
                float g = 1.0f - 2.0f * __builtin_amdgcn_rcpf(
                              1.0f + __builtin_amdgcn_exp2f(ag[nt][r]));
                float hn = g + zs[nt][r] * (hreg[nt][r] - g);
                hreg[nt][r] = hn;
                hn4[r] = hn;
            }
            uint2 p; p.x = pkbf(hn4[0], hn4[1]); p.y = pkbf(hn4[2], hn4[3]);
            hpk[nt] = p;
            *(uint2*)&hA[wro[nt]] = p;
        }
        wg_barrier();   // hA(t) visible for next pass 1 (lgkm-only)

        xz = nz; xr = nr; xg = ng;
    }

    // tail: Hout(TC-1), persist state, emit final hidden on last chunk
    {
        unsigned short* hp = Hout + (size_t)(TC - 1) * 8192 + holane;
        *(uint2*)hp        = hpk[0];
        *(uint2*)(hp + 16) = hpk[1];
    }
    #pragma unroll
    for (int nt = 0; nt < 2; ++nt) {
        int nb = wv * 32 + nt * 16 + qr * 4;
        float4 h4; h4.x = hreg[nt][0]; h4.y = hreg[nt][1]; h4.z = hreg[nt][2]; h4.w = hreg[nt][3];
        *(float4*)(hstate + layer * 8192 + b * 256 + nb) = h4;
        if (last_chunk)
            *(float4*)(dout_tail + (size_t)b * 512 + layer * 256 + nb) = h4;
    }
}

extern "C" void kernel_launch(void* const* d_in, const int* in_sizes, int n_in,
                              void* d_out, int out_size, void* d_ws, size_t ws_size,
                              hipStream_t stream) {
    const float* x   = (const float*)d_in[0];
    const float* h0  = (const float*)d_in[1];
    const float* Wxz = (const float*)d_in[2];
    const float* Whz = (const float*)d_in[3];
    const float* bz  = (const float*)d_in[4];
    const float* Wxr = (const float*)d_in[5];
    const float* Whr = (const float*)d_in[6];
    const float* br  = (const float*)d_in[7];
    const float* Wxg = (const float*)d_in[8];
    const float* Whg = (const float*)d_in[9];
    const float* bg  = (const float*)d_in[10];
    const float* Why = (const float*)d_in[11];
    const float* by  = (const float*)d_in[12];
    float* out = (float*)d_out;

    char* ws = (char*)d_ws;
    unsigned short* bufA = (unsigned short*)(ws);                    // XS0 12,582,912 B
    unsigned short* bufB = (unsigned short*)(ws + 12582912);         // XS1 12,582,912 B
    unsigned short* Hc0  = (unsigned short*)(ws + 25165824);         //  4,194,304 B
    unsigned short* Hc1  = (unsigned short*)(ws + 29360128);         //  4,194,304 B
    float*          hst  = (float*)(ws + 33554432);                  //     65,536 B
    float* dout_tail = out + (size_t)32 * 4096 * 256;

    // chunk-pipelined: iter i computes XS0(i), XS1(i-1), y(i-2) in one gemm
    // dispatch, then scans layer0(i) + layer1(i-1) concurrently.
    for (int i = 0; i <= 17; ++i) {
        gemm3<<<dim3(128, 28), 256, 0, stream>>>(x, Hc0, Hc1,
                                                 Wxz, Wxr, Wxg, bz, br, bg,
                                                 Why, by, bufA, bufB, out, i);
        if (i <= 16)
            scan_dual<<<4, 512, 0, stream>>>(bufA, bufB, Hc0, Hc1, hst, h0,
                                             Whz, Whr, Whg, i, dout_tail);
    }
}